// Round 3
// baseline (6075.171 us; speedup 1.0000x reference)
//
#include <hip/hip_runtime.h>
#include <math.h>

// Soft k-means via bf16 hi/lo 3-product MFMA emulation of fp32.
// N=100000, D=512, K=256, temp=30, 11 iterations.
// Iters 0-9: dist writes r^T as packed (bf16hi<<16|bf16lo) u32 [k][i] into the
// out_r region; update loads A-fragments directly from global (no LDS for r).
// Iter 10: dist writes fp32 r[i][k] (final output); update stages it via LDS.
// All LDS tiles are 128-B rows of packed u32 with XOR chunk swizzle
// (chunk ^= ((row>>3)^row)&7) -> conflict-free staged writes and b128 reads.

#define DIMD 512
#define KCL 256
#define NSPLIT 96
#define SWZ(r) ((((r) >> 3) ^ (r)) & 7)

typedef __attribute__((ext_vector_type(8))) short short8;
typedef __attribute__((ext_vector_type(4))) float float4v;

__device__ __forceinline__ unsigned f2bf_u(float x) {
  union { float f; unsigned u; } v; v.f = x;
  return (v.u + 0x7fff + ((v.u >> 16) & 1)) >> 16;
}
__device__ __forceinline__ float bf2f_u(unsigned b) {
  union { unsigned u; float f; } v; v.u = b << 16; return v.f;
}
__device__ __forceinline__ unsigned packhl(float x) {
  unsigned h = f2bf_u(x);
  unsigned l = f2bf_u(x - bf2f_u(h));
  return (h << 16) | l;
}
// 8 packed u32 -> short8 hi / short8 lo (element j = bf16 of source j)
__device__ __forceinline__ void unpack8(const unsigned* u, short8& hi,
                                        short8& lo) {
  union { unsigned w[4]; short8 s; } H, L;
#pragma unroll
  for (int p = 0; p < 4; ++p) {
    unsigned a = u[2 * p], b = u[2 * p + 1];
    H.w[p] = (a >> 16) | (b & 0xffff0000u);
    L.w[p] = (a & 0xffffu) | (b << 16);
  }
  hi = H.s; lo = L.s;
}

// -------- row norms of data --------
__global__ void row_norms_k(const float* __restrict__ x,
                            float* __restrict__ inv_norm, int n) {
  int wave = threadIdx.x >> 6, lane = threadIdx.x & 63;
  int row = blockIdx.x * 4 + wave;
  if (row >= n) return;
  const float4* xr = (const float4*)(x + (size_t)row * DIMD);
  float4 a = xr[lane];
  float4 b = xr[lane + 64];
  float s = a.x*a.x + a.y*a.y + a.z*a.z + a.w*a.w
          + b.x*b.x + b.y*b.y + b.z*b.z + b.w*b.w;
#pragma unroll
  for (int m = 32; m >= 1; m >>= 1) s += __shfl_xor(s, m);
  if (lane == 0) inv_norm[row] = 1.0f / (sqrtf(s) + 1e-6f);
}

// -------- mu_n = normalize(mu_src [/ colsum]) -> bf16 hi/lo; zero accums ----
__global__ void mu_norm_k(const float* __restrict__ mu_src,
                          const float* __restrict__ colsum_in,
                          short* __restrict__ mu_hi, short* __restrict__ mu_lo,
                          float* __restrict__ mu_acc_z,
                          float* __restrict__ colsum_z, int use_colsum) {
  int k = blockIdx.x, t = threadIdx.x;
  float inv_c = use_colsum ? 1.0f / colsum_in[k] : 1.0f;
  float v0 = mu_src[k * DIMD + t] * inv_c;
  float v1 = mu_src[k * DIMD + t + 256] * inv_c;
  float s = v0 * v0 + v1 * v1;
#pragma unroll
  for (int m = 32; m >= 1; m >>= 1) s += __shfl_xor(s, m);
  __shared__ float sred[4];
  int lane = t & 63, wv = t >> 6;
  if (lane == 0) sred[wv] = s;
  __syncthreads();
  s = sred[0] + sred[1] + sred[2] + sred[3];
  float inv = 1.0f / (sqrtf(s) + 1e-6f);
  float w0 = v0 * inv, w1 = v1 * inv;
  unsigned h0 = f2bf_u(w0), h1 = f2bf_u(w1);
  mu_hi[k * DIMD + t] = (short)h0;
  mu_hi[k * DIMD + t + 256] = (short)h1;
  mu_lo[k * DIMD + t] = (short)f2bf_u(w0 - bf2f_u(h0));
  mu_lo[k * DIMD + t + 256] = (short)f2bf_u(w1 - bf2f_u(h1));
  mu_acc_z[k * DIMD + t] = 0.0f;
  mu_acc_z[k * DIMD + t + 256] = 0.0f;
  if (t == 0) colsum_z[k] = 0.0f;
}

// -------- out_mu = mu_acc / colsum --------
__global__ void final_mu_k(const float* __restrict__ mu_acc,
                           const float* __restrict__ colsum,
                           float* __restrict__ out) {
  int k = blockIdx.x, t = threadIdx.x;
  float ic = 1.0f / colsum[k];
  out[k * DIMD + t] = mu_acc[k * DIMD + t] * ic;
  out[k * DIMD + t + 256] = mu_acc[k * DIMD + t + 256] * ic;
}

// -------- dist: r = softmax(temp * data_n @ mu_n^T); writes r^T or fp32 r ----
// Block: 64 i x 256 k, 4 waves; wave owns k cols wave*64..+63.
// A (data hi/lo) staged in swizzled packed-u32 LDS; B (mu) direct from global.
__global__ __launch_bounds__(256) void dist_mfma_k(
    const float* __restrict__ data, const float* __restrict__ inv_norm,
    const short* __restrict__ mu_hi, const short* __restrict__ mu_lo,
    unsigned* __restrict__ rT, float* __restrict__ r_f32, int write_f32,
    float* __restrict__ colsum, const float* __restrict__ temp_p, int n) {
  __shared__ unsigned a_lds[64][32];  // [i][d-packed u32], 128 B rows, swizzled
  __shared__ float red[64][4];

  int t = threadIdx.x, wave = t >> 6, lane = t & 63, q = lane >> 4,
      lx = lane & 15;
  int i0 = blockIdx.x * 64;
  int arow = t >> 3, achk = t & 7;
  int gi0 = min(i0 + arow, n - 1), gi1 = min(i0 + arow + 32, n - 1);
  float sc0 = inv_norm[gi0], sc1 = inv_norm[gi1];
  const float* p0 = data + (size_t)gi0 * DIMD + achk * 4;
  const float* p1 = data + (size_t)gi1 * DIMD + achk * 4;
  int c0 = (achk ^ SWZ(arow)) * 4;
  int c1 = (achk ^ SWZ(arow + 32)) * 4;

  float4v acc[4][4];
#pragma unroll
  for (int mt = 0; mt < 4; ++mt)
#pragma unroll
    for (int nt = 0; nt < 4; ++nt) acc[mt][nt] = (float4v)0.0f;

  for (int ch = 0; ch < 16; ++ch) {
    int d0 = ch * 32;
    float4 v0 = *(const float4*)(p0 + d0);
    float4 v1 = *(const float4*)(p1 + d0);
    uint4 u0, u1;
    u0.x = packhl(v0.x * sc0); u0.y = packhl(v0.y * sc0);
    u0.z = packhl(v0.z * sc0); u0.w = packhl(v0.w * sc0);
    u1.x = packhl(v1.x * sc1); u1.y = packhl(v1.y * sc1);
    u1.z = packhl(v1.z * sc1); u1.w = packhl(v1.w * sc1);
    *(uint4*)&a_lds[arow][c0] = u0;
    *(uint4*)&a_lds[arow + 32][c1] = u1;
    __syncthreads();

    short8 ah[4], al[4], bh[4], bl[4];
#pragma unroll
    for (int mt = 0; mt < 4; ++mt) {
      int row = mt * 16 + lx, s = SWZ(row);
      unsigned u[8];
      *(uint4*)&u[0] = *(const uint4*)&a_lds[row][((2 * q) ^ s) * 4];
      *(uint4*)&u[4] = *(const uint4*)&a_lds[row][((2 * q + 1) ^ s) * 4];
      unpack8(u, ah[mt], al[mt]);
    }
#pragma unroll
    for (int nt = 0; nt < 4; ++nt) {
      int kr = wave * 64 + nt * 16 + lx;
      bh[nt] = *(const short8*)(mu_hi + (size_t)kr * DIMD + d0 + q * 8);
      bl[nt] = *(const short8*)(mu_lo + (size_t)kr * DIMD + d0 + q * 8);
    }
#pragma unroll
    for (int mt = 0; mt < 4; ++mt)
#pragma unroll
      for (int nt = 0; nt < 4; ++nt) {
        acc[mt][nt] = __builtin_amdgcn_mfma_f32_16x16x32_bf16(
            ah[mt], bh[nt], acc[mt][nt], 0, 0, 0);
        acc[mt][nt] = __builtin_amdgcn_mfma_f32_16x16x32_bf16(
            ah[mt], bl[nt], acc[mt][nt], 0, 0, 0);
        acc[mt][nt] = __builtin_amdgcn_mfma_f32_16x16x32_bf16(
            al[mt], bh[nt], acc[mt][nt], 0, 0, 0);
      }
    __syncthreads();
  }

  // softmax over K=256 per row; |temp*dist| <= ~30.5 so no max-shift needed
  float tempv = temp_p[0];
  float rs[4][4];
#pragma unroll
  for (int mt = 0; mt < 4; ++mt)
#pragma unroll
    for (int reg = 0; reg < 4; ++reg) {
      float s = 0.0f;
#pragma unroll
      for (int nt = 0; nt < 4; ++nt) {
        float e = __expf(tempv * acc[mt][nt][reg]);
        acc[mt][nt][reg] = e;
        s += e;
      }
      s += __shfl_xor(s, 1);
      s += __shfl_xor(s, 2);
      s += __shfl_xor(s, 4);
      s += __shfl_xor(s, 8);
      rs[mt][reg] = s;
    }
  if (lx == 0) {
#pragma unroll
    for (int mt = 0; mt < 4; ++mt)
#pragma unroll
      for (int reg = 0; reg < 4; ++reg)
        red[mt * 16 + q * 4 + reg][wave] = rs[mt][reg];
  }
  __syncthreads();

  float cs[4] = {0.0f, 0.0f, 0.0f, 0.0f};
#pragma unroll
  for (int mt = 0; mt < 4; ++mt)
#pragma unroll
    for (int reg = 0; reg < 4; ++reg) {
      int row = mt * 16 + q * 4 + reg;
      float4 v = *(const float4*)&red[row][0];
      float is = 1.0f / (v.x + v.y + v.z + v.w);
      int gi = i0 + row;
      bool ok = gi < n;
#pragma unroll
      for (int nt = 0; nt < 4; ++nt) {
        float r = acc[mt][nt][reg] * is;
        acc[mt][nt][reg] = r;
        if (ok) cs[nt] += r;
      }
    }
  if (!write_f32) {
#pragma unroll
    for (int mt = 0; mt < 4; ++mt) {
      int ibase = i0 + mt * 16 + q * 4;
      if (ibase < n) {  // n%4==0 so all 4 lanes' regs are in-range
#pragma unroll
        for (int nt = 0; nt < 4; ++nt) {
          int k = wave * 64 + nt * 16 + lx;
          uint4 u;
          u.x = packhl(acc[mt][nt][0]); u.y = packhl(acc[mt][nt][1]);
          u.z = packhl(acc[mt][nt][2]); u.w = packhl(acc[mt][nt][3]);
          *(uint4*)(rT + (size_t)k * n + ibase) = u;
        }
      }
    }
  } else {
#pragma unroll
    for (int mt = 0; mt < 4; ++mt)
#pragma unroll
      for (int reg = 0; reg < 4; ++reg) {
        int gi = i0 + mt * 16 + q * 4 + reg;
        if (gi < n) {
#pragma unroll
          for (int nt = 0; nt < 4; ++nt)
            r_f32[(size_t)gi * KCL + wave * 64 + nt * 16 + lx] =
                acc[mt][nt][reg];
        }
      }
  }
#pragma unroll
  for (int nt = 0; nt < 4; ++nt) {
    cs[nt] += __shfl_xor(cs[nt], 16);
    cs[nt] += __shfl_xor(cs[nt], 32);
  }
  if (q == 0) {
#pragma unroll
    for (int nt = 0; nt < 4; ++nt)
      atomicAdd(&colsum[wave * 64 + nt * 16 + lx], cs[nt]);
  }
}

// -------- mu_acc += r^T @ data_n via MFMA --------
// Block: 128 k x 128 d, 4 waves 2x2. A from r^T global (packed u32) or,
// on the fp32-r iteration, via swizzled LDS. B = x staged in swizzled LDS.
__global__ __launch_bounds__(256) void update_mfma_k(
    const unsigned* __restrict__ rT, const float* __restrict__ r_f32,
    int r_is_f32, const float* __restrict__ data,
    const float* __restrict__ inv_norm, float* __restrict__ mu_acc, int n) {
  __shared__ unsigned xT[128][32];  // [d][i-packed u32], swizzled
  __shared__ unsigned rL[128][32];  // [k][i-packed u32] (fp32-r path only)

  int t = threadIdx.x, wave = t >> 6, lane = t & 63, q = lane >> 4,
      lx = lane & 15;
  int bx = blockIdx.x;
  int k0 = (bx & 1) * 128, d0 = (bx >> 1) * 128;
  int chunk = (n + NSPLIT - 1) / NSPLIT;
  int ibeg = blockIdx.y * chunk;
  int iend = min(ibeg + chunk, n);
  int wk = wave >> 1, wd = wave & 1;
  int dq = t & 31, iq4 = t >> 5;

  float4v acc[4][4];
#pragma unroll
  for (int mt = 0; mt < 4; ++mt)
#pragma unroll
    for (int nt = 0; nt < 4; ++nt) acc[mt][nt] = (float4v)0.0f;

  for (int ib = ibeg; ib < iend; ib += 32) {
    int rem = iend - ib;
    // ---- stage x tile (32 i x 128 d) -> xT[d][i] packed, swizzled ----
    {
      float4 xv[4];
#pragma unroll
      for (int ii = 0; ii < 4; ++ii) {
        int gi = ib + iq4 * 4 + ii;
        if (gi < iend) {
          float4 v = *(const float4*)(data + (size_t)gi * DIMD + d0 + dq * 4);
          float sc = inv_norm[gi];
          v.x *= sc; v.y *= sc; v.z *= sc; v.w *= sc;
          xv[ii] = v;
        } else
          xv[ii] = make_float4(0.f, 0.f, 0.f, 0.f);
      }
#pragma unroll
      for (int r = 0; r < 4; ++r) {
        int d = dq * 4 + r;
        uint4 u;
        u.x = packhl((&xv[0].x)[r]); u.y = packhl((&xv[1].x)[r]);
        u.z = packhl((&xv[2].x)[r]); u.w = packhl((&xv[3].x)[r]);
        *(uint4*)&xT[d][(iq4 ^ SWZ(d)) * 4] = u;
      }
    }
    if (r_is_f32) {  // stage r tile (32 i x 128 k) -> rL[k][i] packed
      float4 rv[4];
#pragma unroll
      for (int ii = 0; ii < 4; ++ii) {
        int gi = ib + iq4 * 4 + ii;
        rv[ii] = (gi < iend)
                     ? *(const float4*)(r_f32 + (size_t)gi * KCL + k0 + dq * 4)
                     : make_float4(0.f, 0.f, 0.f, 0.f);
      }
#pragma unroll
      for (int r = 0; r < 4; ++r) {
        int k = dq * 4 + r;
        uint4 u;
        u.x = packhl((&rv[0].x)[r]); u.y = packhl((&rv[1].x)[r]);
        u.z = packhl((&rv[2].x)[r]); u.w = packhl((&rv[3].x)[r]);
        *(uint4*)&rL[k][(iq4 ^ SWZ(k)) * 4] = u;
      }
    }
    // ---- A-fragments from r^T global (packed-path) ----
    short8 ah[4], al[4];
    if (!r_is_f32) {
#pragma unroll
      for (int mt = 0; mt < 4; ++mt) {
        int kr = k0 + wk * 64 + mt * 16 + lx;
        const unsigned* p = rT + (size_t)kr * n + ib + q * 8;
        unsigned u[8];
        if (rem >= 32) {
          *(uint4*)&u[0] = *(const uint4*)p;
          *(uint4*)&u[4] = *(const uint4*)(p + 4);
        } else {
#pragma unroll
          for (int j = 0; j < 8; ++j) u[j] = (q * 8 + j < rem) ? p[j] : 0u;
        }
        unpack8(u, ah[mt], al[mt]);
      }
    }
    __syncthreads();
    if (r_is_f32) {
#pragma unroll
      for (int mt = 0; mt < 4; ++mt) {
        int kl = wk * 64 + mt * 16 + lx, s = SWZ(kl);
        unsigned u[8];
        *(uint4*)&u[0] = *(const uint4*)&rL[kl][((2 * q) ^ s) * 4];
        *(uint4*)&u[4] = *(const uint4*)&rL[kl][((2 * q + 1) ^ s) * 4];
        unpack8(u, ah[mt], al[mt]);
      }
    }
    short8 bh[4], bl[4];
#pragma unroll
    for (int nt = 0; nt < 4; ++nt) {
      int dl = wd * 64 + nt * 16 + lx, s = SWZ(dl);
      unsigned u[8];
      *(uint4*)&u[0] = *(const uint4*)&xT[dl][((2 * q) ^ s) * 4];
      *(uint4*)&u[4] = *(const uint4*)&xT[dl][((2 * q + 1) ^ s) * 4];
      unpack8(u, bh[nt], bl[nt]);
    }
#pragma unroll
    for (int mt = 0; mt < 4; ++mt)
#pragma unroll
      for (int nt = 0; nt < 4; ++nt) {
        acc[mt][nt] = __builtin_amdgcn_mfma_f32_16x16x32_bf16(
            ah[mt], bh[nt], acc[mt][nt], 0, 0, 0);
        acc[mt][nt] = __builtin_amdgcn_mfma_f32_16x16x32_bf16(
            ah[mt], bl[nt], acc[mt][nt], 0, 0, 0);
        acc[mt][nt] = __builtin_amdgcn_mfma_f32_16x16x32_bf16(
            al[mt], bh[nt], acc[mt][nt], 0, 0, 0);
      }
    __syncthreads();
  }
#pragma unroll
  for (int mt = 0; mt < 4; ++mt)
#pragma unroll
    for (int nt = 0; nt < 4; ++nt)
#pragma unroll
      for (int reg = 0; reg < 4; ++reg) {
        int k = k0 + wk * 64 + mt * 16 + q * 4 + reg;
        int d = d0 + wd * 64 + nt * 16 + lx;
        atomicAdd(&mu_acc[(size_t)k * DIMD + d], acc[mt][nt][reg]);
      }
}

extern "C" void kernel_launch(void* const* d_in, const int* in_sizes, int n_in,
                              void* d_out, int out_size, void* d_ws,
                              size_t ws_size, hipStream_t stream) {
  const float* embeds = (const float*)d_in[0];
  const float* temp_p = (const float*)d_in[1];
  const float* init = (const float*)d_in[2];
  int n = in_sizes[0] / DIMD;  // 100000

  float* out_mu = (float*)d_out;              // [256*512]
  float* out_r = (float*)d_out + KCL * DIMD;  // [n*256]: rT packed / fp32 r

  float* wsf = (float*)d_ws;
  float* inv_norm = wsf;                  // n
  float* mu_acc = wsf + ((n + 3) & ~3);   // 256*512
  float* colsum = mu_acc + KCL * DIMD;    // 256
  short* mu_hi = (short*)(colsum + 256);  // 256*512 bf16
  short* mu_lo = mu_hi + KCL * DIMD;      // 256*512 bf16

  row_norms_k<<<(n + 3) / 4, 256, 0, stream>>>(embeds, inv_norm, n);
  mu_norm_k<<<KCL, 256, 0, stream>>>(init, colsum, mu_hi, mu_lo, mu_acc,
                                     colsum, 0);

  for (int it = 0; it <= 10; ++it) {
    int wf32 = (it == 10) ? 1 : 0;
    dist_mfma_k<<<(n + 63) / 64, 256, 0, stream>>>(
        embeds, inv_norm, mu_hi, mu_lo, (unsigned*)out_r, out_r, wf32, colsum,
        temp_p, n);
    update_mfma_k<<<dim3(8, NSPLIT), 256, 0, stream>>>(
        (const unsigned*)out_r, out_r, wf32, embeds, inv_norm, mu_acc, n);
    if (it < 10) {
      mu_norm_k<<<KCL, 256, 0, stream>>>(mu_acc, colsum, mu_hi, mu_lo, mu_acc,
                                         colsum, 1);
    } else {
      final_mu_k<<<KCL, 256, 0, stream>>>(mu_acc, colsum, out_mu);
    }
  }
}